// Round 20
// baseline (898.406 us; speedup 1.0000x reference)
//
#include <hip/hip_runtime.h>
#include <hip/hip_bf16.h>
#include <hip/hip_fp16.h>

// Problem constants (match reference)
constexpr int Bc = 4, Tc = 4096, Dc = 1024, Hc = 16, Ec = 8;
constexpr int SPANc = 64, NSc = 64, HDc = 64, GHc = 128;
constexpr int NSPAN = 256;            // B*NS
constexpr int MAXMT = 134;            // max 4-selection groups
constexpr int NTILES = 12;            // f32 path: 3072/256
constexpr int NT16 = 24;              // w16 path: 3072/128
constexpr int MTH = (MAXMT + 7) / 8;  // 17 high-groups
constexpr int GRID_W16 = MTH * NT16 * 8;     // 3264
constexpr int CVT_BLOCKS = 2048;
#define FINF_MIN (-3.402823466e38f)

typedef __attribute__((ext_vector_type(8))) _Float16 half8;
typedef __attribute__((ext_vector_type(4))) _Float16 half4;
typedef __attribute__((ext_vector_type(4))) float f32x4;

#define LD4(p) (*reinterpret_cast<const float4*>(p))
#define LDU4(p) (*reinterpret_cast<const uint4*>(p))
#define MFMA16(A, B, C) __builtin_amdgcn_mfma_f32_16x16x32_f16(A, B, C, 0, 0, 0)

// ws layout (bytes):
constexpr size_t OFF_EIDX = 0;                 // int[512]
constexpr size_t OFF_EGW  = 2048;              // float[512]
constexpr size_t OFF_NMT  = 6144;              // int
constexpr size_t OFF_MT   = 6208;              // int[134][8] {e, code0..3, -,-,-}
constexpr size_t OFF_UT   = 65536;             // fp16[512][3072][64], slot=span*2+j
constexpr size_t UT_BYTES = (size_t)NSPAN * 2 * 3072 * 64 * 2;   // 201,326,592
constexpr size_t WS_MID   = OFF_UT + UT_BYTES;                    // ~201.4 MB (f32 path)
constexpr size_t OFF_W16  = WS_MID;                               // fp16[3][8][1024][1024] (x64)
constexpr size_t W16_BYTES = (size_t)3 * Ec * Dc * Dc * 2;        // 50,331,648
constexpr size_t WS_W16   = OFF_W16 + W16_BYTES;                  // ~251.7 MB

// ---------------------------------------------------------------------------
// Kernel 1 (fused): blocks [0,256) = per-span gating; blocks [256, 256+2048)
// = all-3-weight fp32 -> fp16 x64 convert (independent halves; saves ~15us).
// ---------------------------------------------------------------------------
__global__ __launch_bounds__(256) void gate_cvt_kernel(
    const float* __restrict__ x, const int* __restrict__ mask,
    const float* __restrict__ w1, const float* __restrict__ b1,
    const float* __restrict__ w2, const float* __restrict__ b2,
    const float* __restrict__ Wq, const float* __restrict__ Wk,
    const float* __restrict__ Wv,
    int* __restrict__ eidx, float* __restrict__ egw,
    _Float16* __restrict__ W16)
{
  const int tid = threadIdx.x;

  if (blockIdx.x >= NSPAN) {
    // ---- cvtw part ----
    constexpr int EDD8 = Ec * Dc * Dc / 8;     // 2^20
    int i = (blockIdx.x - NSPAN) * 256 + tid;
    const int stride = CVT_BLOCKS * 256;
    for (; i < 3 * EDD8; i += stride) {
      const int mat = i >> 20;
      const int r = i & (EDD8 - 1);
      const float* src = (mat == 0) ? Wq : (mat == 1) ? Wk : Wv;
      const float4 a = LD4(src + (size_t)r * 8);
      const float4 b = LD4(src + (size_t)r * 8 + 4);
      half8 h;
      h[0] = (_Float16)(a.x * 64.f); h[1] = (_Float16)(a.y * 64.f);
      h[2] = (_Float16)(a.z * 64.f); h[3] = (_Float16)(a.w * 64.f);
      h[4] = (_Float16)(b.x * 64.f); h[5] = (_Float16)(b.y * 64.f);
      h[6] = (_Float16)(b.z * 64.f); h[7] = (_Float16)(b.w * 64.f);
      *reinterpret_cast<half8*>(W16 + (size_t)i * 8) = h;
    }
    return;
  }

  // ---- gate part ----
  const int span = blockIdx.x;            // 0..255
  const int b = span / NSc, s = span % NSc;

  __shared__ float mv[SPANc];
  __shared__ float msum_s;
  __shared__ float pooled[Dc];
  __shared__ float hbuf[GHc];
  __shared__ float logits[Ec];

  if (tid < SPANc) mv[tid] = (float)mask[(size_t)b * Tc + s * SPANc + tid];
  __syncthreads();
  if (tid == 0) {
    float ms = 0.f;
    for (int l = 0; l < SPANc; ++l) ms += mv[l];
    msum_s = fmaxf(ms, 1e-9f);
  }
  __syncthreads();

  {  // masked mean pool: each thread owns 4 columns
    const int c0 = tid * 4;
    float a0 = 0.f, a1 = 0.f, a2 = 0.f, a3 = 0.f;
    const float* xb = x + ((size_t)b * Tc + s * SPANc) * Dc + c0;
    for (int l = 0; l < SPANc; ++l) {
      const float m = mv[l];
      const float4 v = *reinterpret_cast<const float4*>(xb + (size_t)l * Dc);
      a0 += v.x * m; a1 += v.y * m; a2 += v.z * m; a3 += v.w * m;
    }
    const float inv = 1.f / msum_s;
    pooled[c0 + 0] = a0 * inv; pooled[c0 + 1] = a1 * inv;
    pooled[c0 + 2] = a2 * inv; pooled[c0 + 3] = a3 * inv;
  }
  __syncthreads();

  if (tid < GHc) {  // hidden layer
    const float* wr = w1 + (size_t)tid * Dc;
    float acc = b1[tid];
    for (int c = 0; c < Dc; c += 4) {
      const float4 w = *reinterpret_cast<const float4*>(wr + c);
      acc += pooled[c] * w.x + pooled[c + 1] * w.y + pooled[c + 2] * w.z + pooled[c + 3] * w.w;
    }
    hbuf[tid] = fmaxf(acc, 0.f);
  }
  __syncthreads();

  if (tid < Ec) {  // logits
    const float* wr = w2 + tid * GHc;
    float acc = b2[tid];
    for (int j = 0; j < GHc; ++j) acc += hbuf[j] * wr[j];
    logits[tid] = acc;
  }
  __syncthreads();

  if (tid == 0) {  // top-2 (ties -> lowest index) + softmax
    int e0 = 0; float v0 = logits[0];
    for (int e = 1; e < Ec; ++e) { if (logits[e] > v0) { v0 = logits[e]; e0 = e; } }
    int e1 = (e0 == 0) ? 1 : 0; float v1 = logits[e1];
    for (int e = 0; e < Ec; ++e) {
      if (e == e0 || e == e1) continue;
      if (logits[e] > v1) { v1 = logits[e]; e1 = e; }
    }
    const float ex = expf(v1 - v0);               // v0 >= v1, stable
    const float den = 1.f + ex;
    eidx[span * 2 + 0] = e0; eidx[span * 2 + 1] = e1;
    egw[span * 2 + 0] = 1.f / den; egw[span * 2 + 1] = ex / den;
  }
}

// ---------------------------------------------------------------------------
// Kernel 1b: bookkeeping — group the 512 (span, sel) pairs by expert into
// groups of 4. mtiles[m] = {e, code0..code3} with code = span*2 + j.
// ---------------------------------------------------------------------------
__global__ __launch_bounds__(64) void bookkeep_kernel(
    const int* __restrict__ eidx, int* __restrict__ nmt, int* __restrict__ mtiles)
{
  __shared__ int codes[Ec][NSPAN * 2];
  __shared__ int cnt[Ec];
  __shared__ int base[Ec + 1];
  const int tid = threadIdx.x;

  if (tid < Ec) {
    int c = 0;
    for (int s = 0; s < NSPAN; ++s) {
      for (int j = 0; j < 2; ++j) {
        if (eidx[s * 2 + j] == tid) codes[tid][c++] = s * 2 + j;
      }
    }
    cnt[tid] = c;
  }
  __syncthreads();
  if (tid == 0) {
    int acc = 0;
    for (int e = 0; e < Ec; ++e) { base[e] = acc; acc += (cnt[e] + 3) >> 2; }
    base[Ec] = acc;
    *nmt = acc;
  }
  __syncthreads();
  if (tid < Ec) {
    const int e = tid, c = cnt[e], ng = (c + 3) >> 2;
    for (int g = 0; g < ng; ++g) {
      const int m = base[e] + g;
      mtiles[m * 8 + 0] = e;
      for (int i = 0; i < 4; ++i) {
        const int li = g * 4 + i;
        mtiles[m * 8 + 1 + i] = codes[e][(li < c) ? li : 0];
      }
    }
  }
}

// ---------------------------------------------------------------------------
// Kernel 2a (W16): R17/R19 config + DOUBLE-BUFFERED LDS, ONE barrier/step
// (64 -> 33 barriers per k-loop). Safety: per-thread order is
// compute(t-1) -> stage(t,bufA) -> barrier(t) -> compute(t) -> stage(t+1,bufB);
// barrier(t) guarantees all compute(t-1) reads of bufB are done before any
// stage(t+1) write. Pinned VGPR prefetch still flies across the barrier
// (VGPR-dest loads don't force the barrier's vmcnt drain).
// BM=256 BN=128 BK=32, 512 thr, acc[4][4], __launch_bounds__(512,4) reg cap
// (128/wave incl acc -> 2 blocks/CU), pad 36, XCD affinity, plain stores.
// LDS 54 KB -> 2 blocks = 108 KB (fits 160).
// ---------------------------------------------------------------------------
__global__ __launch_bounds__(512, 4) void moe_gemm_w16(
    const float* __restrict__ x, const _Float16* __restrict__ W16,
    const int* __restrict__ nmt, const int* __restrict__ mtiles,
    _Float16* __restrict__ Ut)
{
  const int lin = blockIdx.x;              // 0..3263
  const int xcd = lin & 7;
  const int q = lin >> 3;                  // 0..407
  const int mtH = q / NT16;
  const int nt = q % NT16;                 // 0..23
  const int mt = mtH * 8 + xcd;
  if (mt >= *nmt) return;

  const int e = mtiles[mt * 8 + 0];
  int codes[4];
#pragma unroll
  for (int i = 0; i < 4; ++i) codes[i] = mtiles[mt * 8 + 1 + i];

  const int mat = nt >> 3;                 // 0=Q,1=K,2=V
  const int wcol0 = (nt & 7) * 128;
  const _Float16* Wb = W16 + (size_t)mat * ((size_t)Ec * Dc * Dc)
                     + ((size_t)e * Dc + wcol0) * Dc;   // 128 W-rows, fp16 x64

  __shared__ _Float16 As[2][256][36];   // 36 KB
  __shared__ _Float16 Bs[2][128][36];   // 18 KB

  const int t = threadIdx.x;
  // A staging: row = t>>1 (0..255), 16-float chunk = (t&1)*16
  const int arow = t >> 1;
  const int acol0 = (t & 1) * 16;
  const float* asrc =
      x + ((size_t)(codes[arow >> 6] >> 1) * SPANc + (arow & 63)) * Dc + acol0;
  // B staging: row = t>>2 (0..127), 8-half chunk = (t&3)*8
  const int brow = t >> 2;
  const int bcol0 = (t & 3) * 8;
  const _Float16* bsrc = Wb + (size_t)brow * Dc + bcol0;

  const int w = t >> 6, lane = t & 63;
  const int lr = lane & 15, koff = (lane >> 4) * 8;
  const int rbase = (w >> 1) * 64;         // 0,64,128,192
  const int cbase = (w & 1) * 64;          // 0,64

  f32x4 acc[4][4];
#pragma unroll
  for (int ri = 0; ri < 4; ++ri)
#pragma unroll
    for (int ci = 0; ci < 4; ++ci)
#pragma unroll
      for (int j = 0; j < 4; ++j) acc[ri][ci][j] = 0.f;

  // prefetch bank: A = 4 float4, B = 1 uint4
  float4 pa0 = LD4(asrc), pa1 = LD4(asrc + 4), pa2 = LD4(asrc + 8), pa3 = LD4(asrc + 12);
  uint4 pb0 = LDU4(bsrc);

  for (int it = 0; it < 32; ++it) {
    const int cur = it & 1;
    {  // stage A (cvt fp32->fp16) and B (pure copy) into buf[cur]
      half8 ha;
      ha[0] = (_Float16)pa0.x; ha[1] = (_Float16)pa0.y;
      ha[2] = (_Float16)pa0.z; ha[3] = (_Float16)pa0.w;
      ha[4] = (_Float16)pa1.x; ha[5] = (_Float16)pa1.y;
      ha[6] = (_Float16)pa1.z; ha[7] = (_Float16)pa1.w;
      *reinterpret_cast<half8*>(&As[cur][arow][acol0]) = ha;
      ha[0] = (_Float16)pa2.x; ha[1] = (_Float16)pa2.y;
      ha[2] = (_Float16)pa2.z; ha[3] = (_Float16)pa2.w;
      ha[4] = (_Float16)pa3.x; ha[5] = (_Float16)pa3.y;
      ha[6] = (_Float16)pa3.z; ha[7] = (_Float16)pa3.w;
      *reinterpret_cast<half8*>(&As[cur][arow][acol0 + 8]) = ha;
      *reinterpret_cast<uint4*>(&Bs[cur][brow][bcol0]) = pb0;
    }
    if (it < 31) {  // issue next step's loads; pinned so they can't sink
      asrc += 32; bsrc += 32;
      pa0 = LD4(asrc); pa1 = LD4(asrc + 4); pa2 = LD4(asrc + 8); pa3 = LD4(asrc + 12);
      pb0 = LDU4(bsrc);
      __builtin_amdgcn_sched_barrier(0);
    }
    __syncthreads();   // single barrier: staging(cur) visible; next iter
                       // writes the OTHER buffer so no tail barrier needed

    half8 afr[4], bfr[4];
#pragma unroll
    for (int ri = 0; ri < 4; ++ri)
      afr[ri] = *reinterpret_cast<const half8*>(&As[cur][rbase + ri * 16 + lr][koff]);
#pragma unroll
    for (int ci = 0; ci < 4; ++ci)
      bfr[ci] = *reinterpret_cast<const half8*>(&Bs[cur][cbase + ci * 16 + lr][koff]);
    __builtin_amdgcn_s_setprio(1);
#pragma unroll
    for (int ri = 0; ri < 4; ++ri)
#pragma unroll
      for (int ci = 0; ci < 4; ++ci)
        acc[ri][ci] = MFMA16(afr[ri], bfr[ci], acc[ri][ci]);
    __builtin_amdgcn_s_setprio(0);
  }

  // ---- epilogue: Ut transposed per-slot (slot = code), plain stores
#pragma unroll
  for (int ri = 0; ri < 4; ++ri)
#pragma unroll
    for (int ci = 0; ci < 4; ++ci) {
      const int f = wcol0 + cbase + ci * 16 + lr;
      const int row0 = rbase + ri * 16 + (lane >> 4) * 4;
      const int slot = codes[row0 >> 6];
      half4 hv;
#pragma unroll
      for (int j = 0; j < 4; ++j) hv[j] = (_Float16)acc[ri][ci][j];
      *reinterpret_cast<half4*>(
          Ut + ((size_t)slot * 3072 + mat * 1024 + f) * 64 + (row0 & 63)) = hv;
    }
}

// ---------------------------------------------------------------------------
// Kernel 2b (f32 fallback, R6 tiling): grouped GEMM on fp32, cvt in staging.
// ---------------------------------------------------------------------------
__global__ __launch_bounds__(512, 2) void moe_gemm_f32(
    const float* __restrict__ x,
    const float* __restrict__ Wq, const float* __restrict__ Wk,
    const float* __restrict__ Wv,
    const int* __restrict__ nmt, const int* __restrict__ mtiles,
    _Float16* __restrict__ Ut)
{
  const int lin = blockIdx.x + gridDim.x * blockIdx.y;
  const int lin2 = (lin & 7) * 201 + (lin >> 3);
  const int mt = lin2 % MAXMT;
  const int nt = lin2 / MAXMT;
  if (mt >= *nmt) return;

  const int e = mtiles[mt * 8 + 0];
  int codes[4];
#pragma unroll
  for (int i = 0; i < 4; ++i) codes[i] = mtiles[mt * 8 + 1 + i];

  const int mat = nt >> 2;
  const int wcol0 = (nt & 3) * 256;
  const float* Wp = (mat == 0) ? Wq : (mat == 1) ? Wk : Wv;
  const float* Wbase = Wp + ((size_t)e * Dc + wcol0) * Dc;

  __shared__ _Float16 As[256][36];
  __shared__ _Float16 Bs[256][36];

  const int t = threadIdx.x;
  const int arow = t >> 1;
  const int acol0 = (t & 1) * 16;
  const float* asrc =
      x + ((size_t)(codes[arow >> 6] >> 1) * SPANc + (arow & 63)) * Dc + acol0;
  const float* bsrc = Wbase + (size_t)arow * Dc + acol0;

  const int w = t >> 6, lane = t & 63;
  const int lr = lane & 15, koff = (lane >> 4) * 8;
  const int rbase = (w >> 2) * 128;
  const int cbase = (w & 3) * 64;

  f32x4 acc[8][4];
#pragma unroll
  for (int ri = 0; ri < 8; ++ri)
#pragma unroll
    for (int ci = 0; ci < 4; ++ci)
#pragma unroll
      for (int j = 0; j < 4; ++j) acc[ri][ci][j] = 0.f;

  float4 pa0 = LD4(asrc), pa1 = LD4(asrc + 4), pa2 = LD4(asrc + 8), pa3 = LD4(asrc + 12);
  float4 pb0 = LD4(bsrc), pb1 = LD4(bsrc + 4), pb2 = LD4(bsrc + 8), pb3 = LD4(bsrc + 12);

  for (int k0 = 0; k0 < Dc; k0 += 32) {
    __syncthreads();
    {
      half8 ha, hb;
      ha[0] = (_Float16)pa0.x; ha[1] = (_Float16)pa0.y;
      ha[2] = (_Float16)pa0.z; ha[3] = (_Float16)pa0.w;
      ha[4] = (_Float16)pa1.x; ha[5] = (_Float16)pa1.y;
      ha[6] = (_Float16)pa1.z; ha[7] = (_Float16)pa1.w;
      *reinterpret_cast<half8*>(&As[arow][acol0]) = ha;
      ha[0] = (_Float16)pa2.x; ha[1] = (_Float16)pa2.y;
      ha[2] = (_Float16)pa2.z; ha[3] = (_Float16)pa2.w;
      ha[4] = (_Float16)pa3.x; ha[5] = (_Float16)pa3.y;
      ha[6] = (_Float16)pa3.z; ha[7] = (_Float16)pa3.w;
      *reinterpret_cast<half8*>(&As[arow][acol0 + 8]) = ha;
      hb[0] = (_Float16)(pb0.x * 64.f); hb[1] = (_Float16)(pb0.y * 64.f);
      hb[2] = (_Float16)(pb0.z * 64.f); hb[3] = (_Float16)(pb0.w * 64.f);
      hb[4] = (_Float16)(pb1.x * 64.f); hb[5] = (_Float16)(pb1.y * 64.f);
      hb[6] = (_Float16)(pb1.z * 64.f); hb[7] = (_Float16)(pb1.w * 64.f);
      *reinterpret_cast<half8*>(&Bs[arow][acol0]) = hb;
      hb[0] = (_Float16)(pb2.x * 64.f); hb[1] = (_Float16)(pb2.y * 64.f);
      hb[2] = (_Float16)(pb2.z * 64.f); hb[3] = (_Float16)(pb2.w * 64.f);
      hb[4] = (_Float16)(pb3.x * 64.f); hb[5] = (_Float16)(pb3.y * 64.f);
      hb[6] = (_Float16)(pb3.z * 64.f); hb[7] = (_Float16)(pb3.w * 64.f);
      *reinterpret_cast<half8*>(&Bs[arow][acol0 + 8]) = hb;
    }
    if (k0 < Dc - 32) {
      asrc += 32; bsrc += 32;
      pa0 = LD4(asrc); pa1 = LD4(asrc + 4); pa2 = LD4(asrc + 8); pa3 = LD4(asrc + 12);
      pb0 = LD4(bsrc); pb1 = LD4(bsrc + 4); pb2 = LD4(bsrc + 8); pb3 = LD4(bsrc + 12);
      __builtin_amdgcn_sched_barrier(0);
    }
    __syncthreads();

    half8 afr[8], bfr[4];
#pragma unroll
    for (int ri = 0; ri < 8; ++ri)
      afr[ri] = *reinterpret_cast<const half8*>(&As[rbase + ri * 16 + lr][koff]);
#pragma unroll
    for (int ci = 0; ci < 4; ++ci)
      bfr[ci] = *reinterpret_cast<const half8*>(&Bs[cbase + ci * 16 + lr][koff]);
#pragma unroll
    for (int ri = 0; ri < 8; ++ri)
#pragma unroll
      for (int ci = 0; ci < 4; ++ci)
        acc[ri][ci] = MFMA16(afr[ri], bfr[ci], acc[ri][ci]);
  }

#pragma unroll
  for (int ri = 0; ri < 8; ++ri)
#pragma unroll
    for (int ci = 0; ci < 4; ++ci) {
      const int f = wcol0 + cbase + ci * 16 + lr;
      const int row0 = rbase + ri * 16 + (lane >> 4) * 4;
      const int slot = codes[row0 >> 6];
      half4 hv;
#pragma unroll
      for (int j = 0; j < 4; ++j) hv[j] = (_Float16)acc[ri][ci][j];
      *reinterpret_cast<half4*>(
          Ut + ((size_t)slot * 3072 + mat * 1024 + f) * 64 + (row0 & 63)) = hv;
    }
}

// ---------------------------------------------------------------------------
// Kernel 3: attention per (b, span, head). Slots are span*2 and span*2+1.
// ---------------------------------------------------------------------------
__global__ __launch_bounds__(256, 3) void attn_kernel(
    const int* __restrict__ mask, const float* __restrict__ egw,
    const _Float16* __restrict__ Ut, float* __restrict__ out)
{
  const int h = blockIdx.x;
  const int s = blockIdx.y;
  const int b = blockIdx.z;
  const int span = b * NSc + s;
  const int tid = threadIdx.x;

  __shared__ _Float16 Qf[64][68];
  __shared__ _Float16 Kf[64][68];
  __shared__ _Float16 VT[64][68];   // VT[f][m]
  __shared__ _Float16 Pf[64][68];
  __shared__ float    sc[64][68];

  const int sA = span * 2 + 0;
  const int sB = span * 2 + 1;
  const float gA = egw[span * 2 + 0] * 0.015625f;   // /64 (Ut carries x64)
  const float gB = egw[span * 2 + 1] * 0.015625f;

  const int d = tid >> 2;             // feature 0..63
  const int l0 = (tid & 3) * 16;      // token chunk

  for (int mat = 0; mat < 3; ++mat) {
    const _Float16* pa = Ut + ((size_t)sA * 3072 + mat * 1024 + h * HDc + d) * 64 + l0;
    const _Float16* pb = Ut + ((size_t)sB * 3072 + mat * 1024 + h * HDc + d) * 64 + l0;
    const half8 a0 = *reinterpret_cast<const half8*>(pa);
    const half8 a1 = *reinterpret_cast<const half8*>(pa + 8);
    const half8 b0 = *reinterpret_cast<const half8*>(pb);
    const half8 b1 = *reinterpret_cast<const half8*>(pb + 8);
    if (mat == 2) {
      half8 v0, v1;
#pragma unroll
      for (int j = 0; j < 8; ++j) {
        v0[j] = (_Float16)(gA * (float)a0[j] + gB * (float)b0[j]);
        v1[j] = (_Float16)(gA * (float)a1[j] + gB * (float)b1[j]);
      }
      *reinterpret_cast<half8*>(&VT[d][l0]) = v0;
      *reinterpret_cast<half8*>(&VT[d][l0 + 8]) = v1;
    } else if (mat == 0) {
#pragma unroll
      for (int j = 0; j < 8; ++j) {
        Qf[l0 + j][d] = (_Float16)(gA * (float)a0[j] + gB * (float)b0[j]);
        Qf[l0 + 8 + j][d] = (_Float16)(gA * (float)a1[j] + gB * (float)b1[j]);
      }
    } else {
#pragma unroll
      for (int j = 0; j < 8; ++j) {
        Kf[l0 + j][d] = (_Float16)(gA * (float)a0[j] + gB * (float)b0[j]);
        Kf[l0 + 8 + j][d] = (_Float16)(gA * (float)a1[j] + gB * (float)b1[j]);
      }
    }
  }
  __syncthreads();

  const int w = tid >> 6, lane = tid & 63;
  const int lr = lane & 15, koff = (lane >> 4) * 8;
  const int rbase = (w >> 1) * 32, cbase = (w & 1) * 32;

  // ---- scores = Q K^T / 8 via MFMA ----
  {
    f32x4 aS[2][2];
#pragma unroll
    for (int mi = 0; mi < 2; ++mi)
#pragma unroll
      for (int ni = 0; ni < 2; ++ni)
#pragma unroll
        for (int j = 0; j < 4; ++j) aS[mi][ni][j] = 0.f;
#pragma unroll
    for (int kc = 0; kc < 64; kc += 32) {
      const half8 a0 = *reinterpret_cast<const half8*>(&Qf[rbase + lr][kc + koff]);
      const half8 a1 = *reinterpret_cast<const half8*>(&Qf[rbase + 16 + lr][kc + koff]);
      const half8 b0 = *reinterpret_cast<const half8*>(&Kf[cbase + lr][kc + koff]);
      const half8 b1 = *reinterpret_cast<const half8*>(&Kf[cbase + 16 + lr][kc + koff]);
      aS[0][0] = MFMA16(a0, b0, aS[0][0]); aS[0][1] = MFMA16(a0, b1, aS[0][1]);
      aS[1][0] = MFMA16(a1, b0, aS[1][0]); aS[1][1] = MFMA16(a1, b1, aS[1][1]);
    }
    const bool kv0 = mask[(size_t)b * Tc + s * SPANc + cbase + lr] != 0;
    const bool kv1 = mask[(size_t)b * Tc + s * SPANc + cbase + 16 + lr] != 0;
#pragma unroll
    for (int mi = 0; mi < 2; ++mi)
#pragma unroll
      for (int ni = 0; ni < 2; ++ni) {
        const int col = cbase + ni * 16 + lr;
        const int row0 = rbase + mi * 16 + (lane >> 4) * 4;
        const bool kv = (ni == 0) ? kv0 : kv1;
#pragma unroll
        for (int j = 0; j < 4; ++j)
          sc[row0 + j][col] = kv ? aS[mi][ni][j] * 0.125f : FINF_MIN;
      }
  }
  __syncthreads();

  // ---- row softmax (64 lanes, staggered), write P fp16 ----
  if (tid < 64) {
    float mx = FINF_MIN;
    for (int mm = 0; mm < 64; ++mm) {
      const int m = (mm + tid) & 63;
      mx = fmaxf(mx, sc[tid][m]);
    }
    float sum = 0.f;
    for (int mm = 0; mm < 64; ++mm) {
      const int m = (mm + tid) & 63;
      const float e = expf(sc[tid][m] - mx);
      sc[tid][m] = e;
      sum += e;
    }
    const float inv = 1.f / sum;
    for (int mm = 0; mm < 64; ++mm) {
      const int m = (mm + tid) & 63;
      Pf[tid][m] = (_Float16)(sc[tid][m] * inv);
    }
  }
  __syncthreads();

  // ---- ctx = P V via MFMA (B = VT rows) + store ----
  {
    f32x4 aC[2][2];
#pragma unroll
    for (int mi = 0; mi < 2; ++mi)
#pragma unroll
      for (int ni = 0; ni < 2; ++ni)
#pragma unroll
        for (int j = 0; j < 4; ++j) aC[mi][ni][j] = 0.f;
#pragma unroll
    for (int kc = 0; kc < 64; kc += 32) {
      const half8 a0 = *reinterpret_cast<const half8*>(&Pf[rbase + lr][kc + koff]);
      const half8 a1 = *reinterpret_cast<const half8*>(&Pf[rbase + 16 + lr][kc + koff]);
      const half8 b0 = *reinterpret_cast<const half8*>(&VT[cbase + lr][kc + koff]);
      const half8 b1 = *reinterpret_cast<const half8*>(&VT[cbase + 16 + lr][kc + koff]);
      aC[0][0] = MFMA16(a0, b0, aC[0][0]); aC[0][1] = MFMA16(a0, b1, aC[0][1]);
      aC[1][0] = MFMA16(a1, b0, aC[1][0]); aC[1][1] = MFMA16(a1, b1, aC[1][1]);
    }
    float* ob = out + ((size_t)b * Tc + s * SPANc) * Dc + h * HDc;
#pragma unroll
    for (int mi = 0; mi < 2; ++mi)
#pragma unroll
      for (int ni = 0; ni < 2; ++ni) {
        const int col = cbase + ni * 16 + lr;
        const int row0 = rbase + mi * 16 + (lane >> 4) * 4;
#pragma unroll
        for (int j = 0; j < 4; ++j)
          ob[(size_t)(row0 + j) * Dc + col] = aC[mi][ni][j];
      }
  }
}

// ---------------------------------------------------------------------------
// Fallback (R4 path) if ws is too small for the grouped paths.
// ---------------------------------------------------------------------------
__global__ __launch_bounds__(256, 3) void moe_attn_fb(
    const float* __restrict__ x, const int* __restrict__ mask,
    const float* __restrict__ Wq, const float* __restrict__ Wk,
    const float* __restrict__ Wv,
    const int* __restrict__ eidx, const float* __restrict__ egw,
    float* __restrict__ out)
{
  const int h = blockIdx.x;
  const int s = blockIdx.y;
  const int b = blockIdx.z;
  const int span = b * NSc + s;
  const int tid = threadIdx.x;

  __shared__ __align__(16) char smem[52224];
  _Float16* XF  = (_Float16*)(smem);
  _Float16* WHs = (_Float16*)(smem + 5120);
  _Float16* WLs = (_Float16*)(smem + 10240);
  float* qs = (float*)(smem);
  float* ks = (float*)(smem + 17408);
  float* vs = (float*)(smem + 34816);

  const int e0 = eidx[span * 2 + 0];
  const int e1 = eidx[span * 2 + 1];
  const float g0s = egw[span * 2 + 0] * 64.f;
  const float g1s = egw[span * 2 + 1] * 64.f;

  const int lrow = tid >> 2;
  const int kq = (tid & 3) * 8;
  const int stg_off = lrow * 40 + kq;

  const int w = tid >> 6;
  const int lane = tid & 63;
  const int lr = lane & 15;
  const int koff = (lane >> 4) * 8;
  const int rbase = (w >> 1) * 32;
  const int cbase = (w & 1) * 32;

  const float* xb = x + ((size_t)b * Tc + s * SPANc) * Dc;
  const size_t woff0 = ((size_t)e0 * Dc + h * HDc + lrow) * Dc + kq;
  const size_t woff1 = ((size_t)e1 * Dc + h * HDc + lrow) * Dc + kq;

  const float* xcur  = xb + (size_t)lrow * Dc + kq;
  const float* w0cur = Wv + woff0;
  const float* w1cur = Wv + woff1;
  float4 rx0, rx1, ra0, ra1, rb0, rb1;
  rx0 = LD4(xcur); rx1 = LD4(xcur + 4);
  ra0 = LD4(w0cur); ra1 = LD4(w0cur + 4);
  rb0 = LD4(w1cur); rb1 = LD4(w1cur + 4);

  for (int p = 0; p < 3; ++p) {
    f32x4 acc[2][2];
#pragma unroll
    for (int mi = 0; mi < 2; ++mi)
#pragma unroll
      for (int ni = 0; ni < 2; ++ni)
#pragma unroll
        for (int j = 0; j < 4; ++j) acc[mi][ni][j] = 0.f;

    for (int t = 0; t < 32; ++t) {
      __syncthreads();
      {
        half8 hx;
        hx[0] = (_Float16)rx0.x; hx[1] = (_Float16)rx0.y;
        hx[2] = (_Float16)rx0.z; hx[3] = (_Float16)rx0.w;
        hx[4] = (_Float16)rx1.x; hx[5] = (_Float16)rx1.y;
        hx[6] = (_Float16)rx1.z; hx[7] = (_Float16)rx1.w;
        *reinterpret_cast<half8*>(XF + stg_off) = hx;
      }
      {
        float wv[8];
        wv[0] = g0s * ra0.x + g1s * rb0.x; wv[1] = g0s * ra0.y + g1s * rb0.y;
        wv[2] = g0s * ra0.z + g1s * rb0.z; wv[3] = g0s * ra0.w + g1s * rb0.w;
        wv[4] = g0s * ra1.x + g1s * rb1.x; wv[5] = g0s * ra1.y + g1s * rb1.y;
        wv[6] = g0s * ra1.z + g1s * rb1.z; wv[7] = g0s * ra1.w + g1s * rb1.w;
        half8 hw, lw;
#pragma unroll
        for (int i = 0; i < 8; ++i) {
          const _Float16 wh = (_Float16)wv[i];
          hw[i] = wh;
          lw[i] = (_Float16)(wv[i] - (float)wh);
        }
        *reinterpret_cast<half8*>(WHs + stg_off) = hw;
        *reinterpret_cast<half8*>(WLs + stg_off) = lw;
      }
      if (!(p == 2 && t == 31)) {
        if (t < 31) {
          xcur += 32; w0cur += 32; w1cur += 32;
        } else {
          const float* Wn = (p == 0) ? Wk : Wq;
          xcur = xb + (size_t)lrow * Dc + kq;
          w0cur = Wn + woff0;
          w1cur = Wn + woff1;
        }
        rx0 = LD4(xcur); rx1 = LD4(xcur + 4);
        ra0 = LD4(w0cur); ra1 = LD4(w0cur + 4);
        rb0 = LD4(w1cur); rb1 = LD4(w1cur + 4);
      }
      __syncthreads();

      const half8 a0  = *reinterpret_cast<const half8*>(XF  + (rbase + lr) * 40 + koff);
      const half8 a1  = *reinterpret_cast<const half8*>(XF  + (rbase + 16 + lr) * 40 + koff);
      const half8 bh0 = *reinterpret_cast<const half8*>(WHs + (cbase + lr) * 40 + koff);
      const half8 bh1 = *reinterpret_cast<const half8*>(WHs + (cbase + 16 + lr) * 40 + koff);
      const half8 bl0 = *reinterpret_cast<const half8*>(WLs + (cbase + lr) * 40 + koff);
      const half8 bl1 = *reinterpret_cast<const half8*>(WLs + (cbase + 16 + lr) * 40 + koff);

      acc[0][0] = MFMA16(a0, bh0, acc[0][0]);
      acc[0][1] = MFMA16(a0, bh1, acc[0][1]);
      acc[1][0] = MFMA16(a1, bh0, acc[1][0]);
      acc[1][1] = MFMA16(a1, bh1, acc[1][1]);
      acc[0][0] = MFMA16(a0, bl0, acc[0][0]);
      acc[0][1] = MFMA16(a0, bl1, acc[0][1]);
      acc[1][0] = MFMA16(a1, bl0, acc[1][0]);
      acc[1][1] = MFMA16(a1, bl1, acc[1][1]);
    }

    float* dst = (p == 0) ? vs : (p == 1) ? ks : qs;
    if (p == 2) __syncthreads();
#pragma unroll
    for (int mi = 0; mi < 2; ++mi)
#pragma unroll
      for (int ni = 0; ni < 2; ++ni) {
        const int col = cbase + ni * 16 + lr;
        const int row0 = rbase + mi * 16 + (lane >> 4) * 4;
#pragma unroll
        for (int j = 0; j < 4; ++j)
          dst[(row0 + j) * 68 + col] = acc[mi][ni][j] * 0.015625f;
      }
  }
  __syncthreads();

  const int tx = tid & 15;
  const int ty = tid >> 4;
  bool kvalid[4];
#pragma unroll
  for (int j = 0; j < 4; ++j)
    kvalid[j] = mask[(size_t)b * Tc + s * SPANc + tx * 4 + j] != 0;

  float sacc[4][4] = {{0.f, 0.f, 0.f, 0.f}, {0.f, 0.f, 0.f, 0.f},
                      {0.f, 0.f, 0.f, 0.f}, {0.f, 0.f, 0.f, 0.f}};
  for (int dd = 0; dd < 64; ++dd) {
    const int d = (dd + tid) & 63;
    const float a0 = qs[(ty * 4 + 0) * 68 + d], a1 = qs[(ty * 4 + 1) * 68 + d];
    const float a2 = qs[(ty * 4 + 2) * 68 + d], a3 = qs[(ty * 4 + 3) * 68 + d];
    const float b0 = ks[(tx * 4 + 0) * 68 + d], b1v = ks[(tx * 4 + 1) * 68 + d];
    const float b2v = ks[(tx * 4 + 2) * 68 + d], b3 = ks[(tx * 4 + 3) * 68 + d];
    sacc[0][0] += a0 * b0; sacc[0][1] += a0 * b1v; sacc[0][2] += a0 * b2v; sacc[0][3] += a0 * b3;
    sacc[1][0] += a1 * b0; sacc[1][1] += a1 * b1v; sacc[1][2] += a1 * b2v; sacc[1][3] += a1 * b3;
    sacc[2][0] += a2 * b0; sacc[2][1] += a2 * b1v; sacc[2][2] += a2 * b2v; sacc[2][3] += a2 * b3;
    sacc[3][0] += a3 * b0; sacc[3][1] += a3 * b1v; sacc[3][2] += a3 * b2v; sacc[3][3] += a3 * b3;
  }
  __syncthreads();
#pragma unroll
  for (int i = 0; i < 4; ++i)
#pragma unroll
    for (int j = 0; j < 4; ++j)
      qs[(ty * 4 + i) * 68 + tx * 4 + j] = kvalid[j] ? sacc[i][j] * 0.125f : FINF_MIN;
  __syncthreads();

  if (tid < 64) {
    float mx = FINF_MIN;
    for (int mm = 0; mm < 64; ++mm) {
      const int m = (mm + tid) & 63;
      mx = fmaxf(mx, qs[tid * 68 + m]);
    }
    float sum = 0.f;
    for (int mm = 0; mm < 64; ++mm) {
      const int m = (mm + tid) & 63;
      const float e = expf(qs[tid * 68 + m] - mx);
      qs[tid * 68 + m] = e;
      sum += e;
    }
    const float inv = 1.f / sum;
    for (int mm = 0; mm < 64; ++mm) {
      const int m = (mm + tid) & 63;
      qs[tid * 68 + m] *= inv;
    }
  }
  __syncthreads();

  float cacc[4][4] = {{0.f, 0.f, 0.f, 0.f}, {0.f, 0.f, 0.f, 0.f},
                      {0.f, 0.f, 0.f, 0.f}, {0.f, 0.f, 0.f, 0.f}};
  for (int m = 0; m < 64; ++m) {
    const float p0 = qs[(ty * 4 + 0) * 68 + m], p1 = qs[(ty * 4 + 1) * 68 + m];
    const float p2 = qs[(ty * 4 + 2) * 68 + m], p3 = qs[(ty * 4 + 3) * 68 + m];
    const float4 vv = *reinterpret_cast<const float4*>(&vs[m * 68 + tx * 4]);
    cacc[0][0] += p0 * vv.x; cacc[0][1] += p0 * vv.y; cacc[0][2] += p0 * vv.z; cacc[0][3] += p0 * vv.w;
    cacc[1][0] += p1 * vv.x; cacc[1][1] += p1 * vv.y; cacc[1][2] += p1 * vv.z; cacc[1][3] += p1 * vv.w;
    cacc[2][0] += p2 * vv.x; cacc[2][1] += p2 * vv.y; cacc[2][2] += p2 * vv.z; cacc[2][3] += p2 * vv.w;
    cacc[3][0] += p3 * vv.x; cacc[3][1] += p3 * vv.y; cacc[3][2] += p3 * vv.z; cacc[3][3] += p3 * vv.w;
  }

  float* ob = out + ((size_t)b * Tc + s * SPANc) * Dc + h * HDc;
#pragma unroll
  for (int i = 0; i < 4; ++i) {
    *reinterpret_cast<float4*>(ob + (size_t)(ty * 4 + i) * Dc + tx * 4) =
        make_float4(cacc[i][0], cacc[i][1], cacc[i][2], cacc[i][3]);
  }
}

// ---------------------------------------------------------------------------
extern "C" void kernel_launch(void* const* d_in, const int* in_sizes, int n_in,
                              void* d_out, int out_size, void* d_ws, size_t ws_size,
                              hipStream_t stream) {
  const float* x   = (const float*)d_in[0];
  const int*   msk = (const int*)d_in[1];
  const float* Wq  = (const float*)d_in[2];
  const float* Wk  = (const float*)d_in[3];
  const float* Wv  = (const float*)d_in[4];
  const float* w1  = (const float*)d_in[5];
  const float* b1  = (const float*)d_in[6];
  const float* w2  = (const float*)d_in[7];
  const float* b2  = (const float*)d_in[8];
  float* out = (float*)d_out;

  char* ws = (char*)d_ws;
  int*      eidx   = (int*)(ws + OFF_EIDX);
  float*    egw    = (float*)(ws + OFF_EGW);
  int*      nmt    = (int*)(ws + OFF_NMT);
  int*      mtiles = (int*)(ws + OFF_MT);
  _Float16* Ut     = (_Float16*)(ws + OFF_UT);
  _Float16* W16    = (_Float16*)(ws + OFF_W16);

  if (ws_size >= WS_W16) {
    gate_cvt_kernel<<<NSPAN + CVT_BLOCKS, 256, 0, stream>>>(
        x, msk, w1, b1, w2, b2, Wq, Wk, Wv, eidx, egw, W16);
    bookkeep_kernel<<<1, 64, 0, stream>>>(eidx, nmt, mtiles);
    moe_gemm_w16<<<GRID_W16, 512, 0, stream>>>(x, W16, nmt, mtiles, Ut);
    attn_kernel<<<dim3(Hc, NSc, Bc), 256, 0, stream>>>(msk, egw, Ut, out);
  } else if (ws_size >= WS_MID) {
    gate_cvt_kernel<<<NSPAN, 256, 0, stream>>>(
        x, msk, w1, b1, w2, b2, Wq, Wk, Wv, eidx, egw, nullptr);
    bookkeep_kernel<<<1, 64, 0, stream>>>(eidx, nmt, mtiles);
    moe_gemm_f32<<<dim3(MAXMT, NTILES), 512, 0, stream>>>(
        x, Wq, Wk, Wv, nmt, mtiles, Ut);
    attn_kernel<<<dim3(Hc, NSc, Bc), 256, 0, stream>>>(msk, egw, Ut, out);
  } else {
    gate_cvt_kernel<<<NSPAN, 256, 0, stream>>>(
        x, msk, w1, b1, w2, b2, Wq, Wk, Wv, eidx, egw, nullptr);
    moe_attn_fb<<<dim3(Hc, NSc, Bc), 256, 0, stream>>>(
        x, msk, Wq, Wk, Wv, eidx, egw, out);
  }
}

// Round 21
// 485.004 us; speedup vs baseline: 1.8524x; 1.8524x over previous
//
#include <hip/hip_runtime.h>
#include <hip/hip_bf16.h>
#include <hip/hip_fp16.h>

// Problem constants (match reference)
constexpr int Bc = 4, Tc = 4096, Dc = 1024, Hc = 16, Ec = 8;
constexpr int SPANc = 64, NSc = 64, HDc = 64, GHc = 128;
constexpr int NSPAN = 256;            // B*NS
constexpr int MAXMT = 134;            // max 4-selection groups
constexpr int NTILES = 12;            // f32 path: 3072/256
constexpr int NT16 = 24;              // w16 path: 3072/128
constexpr int MTH = (MAXMT + 7) / 8;  // 17 high-groups
constexpr int GRID_W16 = MTH * NT16 * 8;     // 3264
constexpr int CVT_BLOCKS = 2048;
#define FINF_MIN (-3.402823466e38f)

typedef __attribute__((ext_vector_type(8))) _Float16 half8;
typedef __attribute__((ext_vector_type(4))) _Float16 half4;
typedef __attribute__((ext_vector_type(4))) float f32x4;

#define LD4(p) (*reinterpret_cast<const float4*>(p))
#define LDU4(p) (*reinterpret_cast<const uint4*>(p))
#define MFMA16(A, B, C) __builtin_amdgcn_mfma_f32_16x16x32_f16(A, B, C, 0, 0, 0)

// ws layout (bytes):
constexpr size_t OFF_EIDX = 0;                 // int[512]
constexpr size_t OFF_EGW  = 2048;              // float[512]
constexpr size_t OFF_NMT  = 6144;              // int
constexpr size_t OFF_MT   = 6208;              // int[134][8] {e, code0..3, -,-,-}
constexpr size_t OFF_UT   = 65536;             // fp16[512][3072][64], slot=span*2+j
constexpr size_t UT_BYTES = (size_t)NSPAN * 2 * 3072 * 64 * 2;   // 201,326,592
constexpr size_t WS_MID   = OFF_UT + UT_BYTES;                    // ~201.4 MB (f32 path)
constexpr size_t OFF_W16  = WS_MID;                               // fp16[3][8][1024][1024] (x64)
constexpr size_t W16_BYTES = (size_t)3 * Ec * Dc * Dc * 2;        // 50,331,648
constexpr size_t WS_W16   = OFF_W16 + W16_BYTES;                  // ~251.7 MB

// ---------------------------------------------------------------------------
// Kernel 1 (fused): blocks [0,256) = per-span gating; blocks [256, 256+2048)
// = all-3-weight fp32 -> fp16 x64 convert (independent halves; saves ~15us).
// ---------------------------------------------------------------------------
__global__ __launch_bounds__(256) void gate_cvt_kernel(
    const float* __restrict__ x, const int* __restrict__ mask,
    const float* __restrict__ w1, const float* __restrict__ b1,
    const float* __restrict__ w2, const float* __restrict__ b2,
    const float* __restrict__ Wq, const float* __restrict__ Wk,
    const float* __restrict__ Wv,
    int* __restrict__ eidx, float* __restrict__ egw,
    _Float16* __restrict__ W16)
{
  const int tid = threadIdx.x;

  if (blockIdx.x >= NSPAN) {
    // ---- cvtw part ----
    constexpr int EDD8 = Ec * Dc * Dc / 8;     // 2^20
    int i = (blockIdx.x - NSPAN) * 256 + tid;
    const int stride = CVT_BLOCKS * 256;
    for (; i < 3 * EDD8; i += stride) {
      const int mat = i >> 20;
      const int r = i & (EDD8 - 1);
      const float* src = (mat == 0) ? Wq : (mat == 1) ? Wk : Wv;
      const float4 a = LD4(src + (size_t)r * 8);
      const float4 b = LD4(src + (size_t)r * 8 + 4);
      half8 h;
      h[0] = (_Float16)(a.x * 64.f); h[1] = (_Float16)(a.y * 64.f);
      h[2] = (_Float16)(a.z * 64.f); h[3] = (_Float16)(a.w * 64.f);
      h[4] = (_Float16)(b.x * 64.f); h[5] = (_Float16)(b.y * 64.f);
      h[6] = (_Float16)(b.z * 64.f); h[7] = (_Float16)(b.w * 64.f);
      *reinterpret_cast<half8*>(W16 + (size_t)i * 8) = h;
    }
    return;
  }

  // ---- gate part ----
  const int span = blockIdx.x;            // 0..255
  const int b = span / NSc, s = span % NSc;

  __shared__ float mv[SPANc];
  __shared__ float msum_s;
  __shared__ float pooled[Dc];
  __shared__ float hbuf[GHc];
  __shared__ float logits[Ec];

  if (tid < SPANc) mv[tid] = (float)mask[(size_t)b * Tc + s * SPANc + tid];
  __syncthreads();
  if (tid == 0) {
    float ms = 0.f;
    for (int l = 0; l < SPANc; ++l) ms += mv[l];
    msum_s = fmaxf(ms, 1e-9f);
  }
  __syncthreads();

  {  // masked mean pool: each thread owns 4 columns
    const int c0 = tid * 4;
    float a0 = 0.f, a1 = 0.f, a2 = 0.f, a3 = 0.f;
    const float* xb = x + ((size_t)b * Tc + s * SPANc) * Dc + c0;
    for (int l = 0; l < SPANc; ++l) {
      const float m = mv[l];
      const float4 v = *reinterpret_cast<const float4*>(xb + (size_t)l * Dc);
      a0 += v.x * m; a1 += v.y * m; a2 += v.z * m; a3 += v.w * m;
    }
    const float inv = 1.f / msum_s;
    pooled[c0 + 0] = a0 * inv; pooled[c0 + 1] = a1 * inv;
    pooled[c0 + 2] = a2 * inv; pooled[c0 + 3] = a3 * inv;
  }
  __syncthreads();

  if (tid < GHc) {  // hidden layer
    const float* wr = w1 + (size_t)tid * Dc;
    float acc = b1[tid];
    for (int c = 0; c < Dc; c += 4) {
      const float4 w = *reinterpret_cast<const float4*>(wr + c);
      acc += pooled[c] * w.x + pooled[c + 1] * w.y + pooled[c + 2] * w.z + pooled[c + 3] * w.w;
    }
    hbuf[tid] = fmaxf(acc, 0.f);
  }
  __syncthreads();

  if (tid < Ec) {  // logits
    const float* wr = w2 + tid * GHc;
    float acc = b2[tid];
    for (int j = 0; j < GHc; ++j) acc += hbuf[j] * wr[j];
    logits[tid] = acc;
  }
  __syncthreads();

  if (tid == 0) {  // top-2 (ties -> lowest index) + softmax
    int e0 = 0; float v0 = logits[0];
    for (int e = 1; e < Ec; ++e) { if (logits[e] > v0) { v0 = logits[e]; e0 = e; } }
    int e1 = (e0 == 0) ? 1 : 0; float v1 = logits[e1];
    for (int e = 0; e < Ec; ++e) {
      if (e == e0 || e == e1) continue;
      if (logits[e] > v1) { v1 = logits[e]; e1 = e; }
    }
    const float ex = expf(v1 - v0);               // v0 >= v1, stable
    const float den = 1.f + ex;
    eidx[span * 2 + 0] = e0; eidx[span * 2 + 1] = e1;
    egw[span * 2 + 0] = 1.f / den; egw[span * 2 + 1] = ex / den;
  }
}

// ---------------------------------------------------------------------------
// Kernel 1b: bookkeeping — group the 512 (span, sel) pairs by expert into
// groups of 4. mtiles[m] = {e, code0..code3} with code = span*2 + j.
// ---------------------------------------------------------------------------
__global__ __launch_bounds__(64) void bookkeep_kernel(
    const int* __restrict__ eidx, int* __restrict__ nmt, int* __restrict__ mtiles)
{
  __shared__ int codes[Ec][NSPAN * 2];
  __shared__ int cnt[Ec];
  __shared__ int base[Ec + 1];
  const int tid = threadIdx.x;

  if (tid < Ec) {
    int c = 0;
    for (int s = 0; s < NSPAN; ++s) {
      for (int j = 0; j < 2; ++j) {
        if (eidx[s * 2 + j] == tid) codes[tid][c++] = s * 2 + j;
      }
    }
    cnt[tid] = c;
  }
  __syncthreads();
  if (tid == 0) {
    int acc = 0;
    for (int e = 0; e < Ec; ++e) { base[e] = acc; acc += (cnt[e] + 3) >> 2; }
    base[Ec] = acc;
    *nmt = acc;
  }
  __syncthreads();
  if (tid < Ec) {
    const int e = tid, c = cnt[e], ng = (c + 3) >> 2;
    for (int g = 0; g < ng; ++g) {
      const int m = base[e] + g;
      mtiles[m * 8 + 0] = e;
      for (int i = 0; i < 4; ++i) {
        const int li = g * 4 + i;
        mtiles[m * 8 + 1 + i] = codes[e][(li < c) ? li : 0];
      }
    }
  }
}

// ---------------------------------------------------------------------------
// Kernel 2a (W16) — champion config (R17/R19, 340us): BM=256 BN=128 BK=32,
// 512 thr / 8 waves, wave-tile 64x64 -> acc[4][4]. __launch_bounds__(512,4)
// caps regs at 128/wave incl. acc -> 2 blocks/CU (41% occ). Pad 36, XCD
// affinity (24 n-tiles of a group 8 apart -> same XCD, A-panel L2-resident),
// 1-deep pinned reg prefetch, 2 barriers/step (1-barrier dbuf regresses:
// R7/R20 — the compiler's pre-barrier vmcnt drain lands right after load
// issue and serializes every step), plain stores.
// ---------------------------------------------------------------------------
__global__ __launch_bounds__(512, 4) void moe_gemm_w16(
    const float* __restrict__ x, const _Float16* __restrict__ W16,
    const int* __restrict__ nmt, const int* __restrict__ mtiles,
    _Float16* __restrict__ Ut)
{
  const int lin = blockIdx.x;              // 0..3263
  const int xcd = lin & 7;
  const int q = lin >> 3;                  // 0..407
  const int mtH = q / NT16;
  const int nt = q % NT16;                 // 0..23
  const int mt = mtH * 8 + xcd;
  if (mt >= *nmt) return;

  const int e = mtiles[mt * 8 + 0];
  int codes[4];
#pragma unroll
  for (int i = 0; i < 4; ++i) codes[i] = mtiles[mt * 8 + 1 + i];

  const int mat = nt >> 3;                 // 0=Q,1=K,2=V
  const int wcol0 = (nt & 7) * 128;
  const _Float16* Wb = W16 + (size_t)mat * ((size_t)Ec * Dc * Dc)
                     + ((size_t)e * Dc + wcol0) * Dc;   // 128 W-rows, fp16 x64

  __shared__ _Float16 As[256][36];   // 18 KB
  __shared__ _Float16 Bs[128][36];   // 9 KB

  const int t = threadIdx.x;
  // A staging: row = t>>1 (0..255), 16-float chunk = (t&1)*16
  const int arow = t >> 1;
  const int acol0 = (t & 1) * 16;
  const float* asrc =
      x + ((size_t)(codes[arow >> 6] >> 1) * SPANc + (arow & 63)) * Dc + acol0;
  // B staging: row = t>>2 (0..127), 8-half chunk = (t&3)*8
  const int brow = t >> 2;
  const int bcol0 = (t & 3) * 8;
  const _Float16* bsrc = Wb + (size_t)brow * Dc + bcol0;

  const int w = t >> 6, lane = t & 63;
  const int lr = lane & 15, koff = (lane >> 4) * 8;
  const int rbase = (w >> 1) * 64;         // 0,64,128,192
  const int cbase = (w & 1) * 64;          // 0,64

  f32x4 acc[4][4];
#pragma unroll
  for (int ri = 0; ri < 4; ++ri)
#pragma unroll
    for (int ci = 0; ci < 4; ++ci)
#pragma unroll
      for (int j = 0; j < 4; ++j) acc[ri][ci][j] = 0.f;

  // prefetch bank: A = 4 float4, B = 1 uint4
  float4 pa0 = LD4(asrc), pa1 = LD4(asrc + 4), pa2 = LD4(asrc + 8), pa3 = LD4(asrc + 12);
  uint4 pb0 = LDU4(bsrc);

  for (int k0 = 0; k0 < Dc; k0 += 32) {
    __syncthreads();   // previous step's frag reads complete
    {  // stage A (cvt fp32->fp16) and B (pure copy)
      half8 ha;
      ha[0] = (_Float16)pa0.x; ha[1] = (_Float16)pa0.y;
      ha[2] = (_Float16)pa0.z; ha[3] = (_Float16)pa0.w;
      ha[4] = (_Float16)pa1.x; ha[5] = (_Float16)pa1.y;
      ha[6] = (_Float16)pa1.z; ha[7] = (_Float16)pa1.w;
      *reinterpret_cast<half8*>(&As[arow][acol0]) = ha;
      ha[0] = (_Float16)pa2.x; ha[1] = (_Float16)pa2.y;
      ha[2] = (_Float16)pa2.z; ha[3] = (_Float16)pa2.w;
      ha[4] = (_Float16)pa3.x; ha[5] = (_Float16)pa3.y;
      ha[6] = (_Float16)pa3.z; ha[7] = (_Float16)pa3.w;
      *reinterpret_cast<half8*>(&As[arow][acol0 + 8]) = ha;
      *reinterpret_cast<uint4*>(&Bs[brow][bcol0]) = pb0;
    }
    if (k0 < Dc - 32) {  // issue next step's loads; pinned so they can't sink
      asrc += 32; bsrc += 32;
      pa0 = LD4(asrc); pa1 = LD4(asrc + 4); pa2 = LD4(asrc + 8); pa3 = LD4(asrc + 12);
      pb0 = LDU4(bsrc);
      __builtin_amdgcn_sched_barrier(0);
    }
    __syncthreads();   // staging visible

    half8 afr[4], bfr[4];
#pragma unroll
    for (int ri = 0; ri < 4; ++ri)
      afr[ri] = *reinterpret_cast<const half8*>(&As[rbase + ri * 16 + lr][koff]);
#pragma unroll
    for (int ci = 0; ci < 4; ++ci)
      bfr[ci] = *reinterpret_cast<const half8*>(&Bs[cbase + ci * 16 + lr][koff]);
    __builtin_amdgcn_s_setprio(1);
#pragma unroll
    for (int ri = 0; ri < 4; ++ri)
#pragma unroll
      for (int ci = 0; ci < 4; ++ci)
        acc[ri][ci] = MFMA16(afr[ri], bfr[ci], acc[ri][ci]);
    __builtin_amdgcn_s_setprio(0);
  }

  // ---- epilogue: Ut transposed per-slot (slot = code), plain stores
#pragma unroll
  for (int ri = 0; ri < 4; ++ri)
#pragma unroll
    for (int ci = 0; ci < 4; ++ci) {
      const int f = wcol0 + cbase + ci * 16 + lr;
      const int row0 = rbase + ri * 16 + (lane >> 4) * 4;
      const int slot = codes[row0 >> 6];
      half4 hv;
#pragma unroll
      for (int j = 0; j < 4; ++j) hv[j] = (_Float16)acc[ri][ci][j];
      *reinterpret_cast<half4*>(
          Ut + ((size_t)slot * 3072 + mat * 1024 + f) * 64 + (row0 & 63)) = hv;
    }
}

// ---------------------------------------------------------------------------
// Kernel 2b (f32 fallback, R6 tiling): grouped GEMM on fp32, cvt in staging.
// ---------------------------------------------------------------------------
__global__ __launch_bounds__(512, 2) void moe_gemm_f32(
    const float* __restrict__ x,
    const float* __restrict__ Wq, const float* __restrict__ Wk,
    const float* __restrict__ Wv,
    const int* __restrict__ nmt, const int* __restrict__ mtiles,
    _Float16* __restrict__ Ut)
{
  const int lin = blockIdx.x + gridDim.x * blockIdx.y;
  const int lin2 = (lin & 7) * 201 + (lin >> 3);
  const int mt = lin2 % MAXMT;
  const int nt = lin2 / MAXMT;
  if (mt >= *nmt) return;

  const int e = mtiles[mt * 8 + 0];
  int codes[4];
#pragma unroll
  for (int i = 0; i < 4; ++i) codes[i] = mtiles[mt * 8 + 1 + i];

  const int mat = nt >> 2;
  const int wcol0 = (nt & 3) * 256;
  const float* Wp = (mat == 0) ? Wq : (mat == 1) ? Wk : Wv;
  const float* Wbase = Wp + ((size_t)e * Dc + wcol0) * Dc;

  __shared__ _Float16 As[256][36];
  __shared__ _Float16 Bs[256][36];

  const int t = threadIdx.x;
  const int arow = t >> 1;
  const int acol0 = (t & 1) * 16;
  const float* asrc =
      x + ((size_t)(codes[arow >> 6] >> 1) * SPANc + (arow & 63)) * Dc + acol0;
  const float* bsrc = Wbase + (size_t)arow * Dc + acol0;

  const int w = t >> 6, lane = t & 63;
  const int lr = lane & 15, koff = (lane >> 4) * 8;
  const int rbase = (w >> 2) * 128;
  const int cbase = (w & 3) * 64;

  f32x4 acc[8][4];
#pragma unroll
  for (int ri = 0; ri < 8; ++ri)
#pragma unroll
    for (int ci = 0; ci < 4; ++ci)
#pragma unroll
      for (int j = 0; j < 4; ++j) acc[ri][ci][j] = 0.f;

  float4 pa0 = LD4(asrc), pa1 = LD4(asrc + 4), pa2 = LD4(asrc + 8), pa3 = LD4(asrc + 12);
  float4 pb0 = LD4(bsrc), pb1 = LD4(bsrc + 4), pb2 = LD4(bsrc + 8), pb3 = LD4(bsrc + 12);

  for (int k0 = 0; k0 < Dc; k0 += 32) {
    __syncthreads();
    {
      half8 ha, hb;
      ha[0] = (_Float16)pa0.x; ha[1] = (_Float16)pa0.y;
      ha[2] = (_Float16)pa0.z; ha[3] = (_Float16)pa0.w;
      ha[4] = (_Float16)pa1.x; ha[5] = (_Float16)pa1.y;
      ha[6] = (_Float16)pa1.z; ha[7] = (_Float16)pa1.w;
      *reinterpret_cast<half8*>(&As[arow][acol0]) = ha;
      ha[0] = (_Float16)pa2.x; ha[1] = (_Float16)pa2.y;
      ha[2] = (_Float16)pa2.z; ha[3] = (_Float16)pa2.w;
      ha[4] = (_Float16)pa3.x; ha[5] = (_Float16)pa3.y;
      ha[6] = (_Float16)pa3.z; ha[7] = (_Float16)pa3.w;
      *reinterpret_cast<half8*>(&As[arow][acol0 + 8]) = ha;
      hb[0] = (_Float16)(pb0.x * 64.f); hb[1] = (_Float16)(pb0.y * 64.f);
      hb[2] = (_Float16)(pb0.z * 64.f); hb[3] = (_Float16)(pb0.w * 64.f);
      hb[4] = (_Float16)(pb1.x * 64.f); hb[5] = (_Float16)(pb1.y * 64.f);
      hb[6] = (_Float16)(pb1.z * 64.f); hb[7] = (_Float16)(pb1.w * 64.f);
      *reinterpret_cast<half8*>(&Bs[arow][acol0]) = hb;
      hb[0] = (_Float16)(pb2.x * 64.f); hb[1] = (_Float16)(pb2.y * 64.f);
      hb[2] = (_Float16)(pb2.z * 64.f); hb[3] = (_Float16)(pb2.w * 64.f);
      hb[4] = (_Float16)(pb3.x * 64.f); hb[5] = (_Float16)(pb3.y * 64.f);
      hb[6] = (_Float16)(pb3.z * 64.f); hb[7] = (_Float16)(pb3.w * 64.f);
      *reinterpret_cast<half8*>(&Bs[arow][acol0 + 8]) = hb;
    }
    if (k0 < Dc - 32) {
      asrc += 32; bsrc += 32;
      pa0 = LD4(asrc); pa1 = LD4(asrc + 4); pa2 = LD4(asrc + 8); pa3 = LD4(asrc + 12);
      pb0 = LD4(bsrc); pb1 = LD4(bsrc + 4); pb2 = LD4(bsrc + 8); pb3 = LD4(bsrc + 12);
      __builtin_amdgcn_sched_barrier(0);
    }
    __syncthreads();

    half8 afr[8], bfr[4];
#pragma unroll
    for (int ri = 0; ri < 8; ++ri)
      afr[ri] = *reinterpret_cast<const half8*>(&As[rbase + ri * 16 + lr][koff]);
#pragma unroll
    for (int ci = 0; ci < 4; ++ci)
      bfr[ci] = *reinterpret_cast<const half8*>(&Bs[cbase + ci * 16 + lr][koff]);
#pragma unroll
    for (int ri = 0; ri < 8; ++ri)
#pragma unroll
      for (int ci = 0; ci < 4; ++ci)
        acc[ri][ci] = MFMA16(afr[ri], bfr[ci], acc[ri][ci]);
  }

#pragma unroll
  for (int ri = 0; ri < 8; ++ri)
#pragma unroll
    for (int ci = 0; ci < 4; ++ci) {
      const int f = wcol0 + cbase + ci * 16 + lr;
      const int row0 = rbase + ri * 16 + (lane >> 4) * 4;
      const int slot = codes[row0 >> 6];
      half4 hv;
#pragma unroll
      for (int j = 0; j < 4; ++j) hv[j] = (_Float16)acc[ri][ci][j];
      *reinterpret_cast<half4*>(
          Ut + ((size_t)slot * 3072 + mat * 1024 + f) * 64 + (row0 & 63)) = hv;
    }
}

// ---------------------------------------------------------------------------
// Kernel 3: attention per (b, span, head). Slots are span*2 and span*2+1.
// ---------------------------------------------------------------------------
__global__ __launch_bounds__(256, 3) void attn_kernel(
    const int* __restrict__ mask, const float* __restrict__ egw,
    const _Float16* __restrict__ Ut, float* __restrict__ out)
{
  const int h = blockIdx.x;
  const int s = blockIdx.y;
  const int b = blockIdx.z;
  const int span = b * NSc + s;
  const int tid = threadIdx.x;

  __shared__ _Float16 Qf[64][68];
  __shared__ _Float16 Kf[64][68];
  __shared__ _Float16 VT[64][68];   // VT[f][m]
  __shared__ _Float16 Pf[64][68];
  __shared__ float    sc[64][68];

  const int sA = span * 2 + 0;
  const int sB = span * 2 + 1;
  const float gA = egw[span * 2 + 0] * 0.015625f;   // /64 (Ut carries x64)
  const float gB = egw[span * 2 + 1] * 0.015625f;

  const int d = tid >> 2;             // feature 0..63
  const int l0 = (tid & 3) * 16;      // token chunk

  for (int mat = 0; mat < 3; ++mat) {
    const _Float16* pa = Ut + ((size_t)sA * 3072 + mat * 1024 + h * HDc + d) * 64 + l0;
    const _Float16* pb = Ut + ((size_t)sB * 3072 + mat * 1024 + h * HDc + d) * 64 + l0;
    const half8 a0 = *reinterpret_cast<const half8*>(pa);
    const half8 a1 = *reinterpret_cast<const half8*>(pa + 8);
    const half8 b0 = *reinterpret_cast<const half8*>(pb);
    const half8 b1 = *reinterpret_cast<const half8*>(pb + 8);
    if (mat == 2) {
      half8 v0, v1;
#pragma unroll
      for (int j = 0; j < 8; ++j) {
        v0[j] = (_Float16)(gA * (float)a0[j] + gB * (float)b0[j]);
        v1[j] = (_Float16)(gA * (float)a1[j] + gB * (float)b1[j]);
      }
      *reinterpret_cast<half8*>(&VT[d][l0]) = v0;
      *reinterpret_cast<half8*>(&VT[d][l0 + 8]) = v1;
    } else if (mat == 0) {
#pragma unroll
      for (int j = 0; j < 8; ++j) {
        Qf[l0 + j][d] = (_Float16)(gA * (float)a0[j] + gB * (float)b0[j]);
        Qf[l0 + 8 + j][d] = (_Float16)(gA * (float)a1[j] + gB * (float)b1[j]);
      }
    } else {
#pragma unroll
      for (int j = 0; j < 8; ++j) {
        Kf[l0 + j][d] = (_Float16)(gA * (float)a0[j] + gB * (float)b0[j]);
        Kf[l0 + 8 + j][d] = (_Float16)(gA * (float)a1[j] + gB * (float)b1[j]);
      }
    }
  }
  __syncthreads();

  const int w = tid >> 6, lane = tid & 63;
  const int lr = lane & 15, koff = (lane >> 4) * 8;
  const int rbase = (w >> 1) * 32, cbase = (w & 1) * 32;

  // ---- scores = Q K^T / 8 via MFMA ----
  {
    f32x4 aS[2][2];
#pragma unroll
    for (int mi = 0; mi < 2; ++mi)
#pragma unroll
      for (int ni = 0; ni < 2; ++ni)
#pragma unroll
        for (int j = 0; j < 4; ++j) aS[mi][ni][j] = 0.f;
#pragma unroll
    for (int kc = 0; kc < 64; kc += 32) {
      const half8 a0 = *reinterpret_cast<const half8*>(&Qf[rbase + lr][kc + koff]);
      const half8 a1 = *reinterpret_cast<const half8*>(&Qf[rbase + 16 + lr][kc + koff]);
      const half8 b0 = *reinterpret_cast<const half8*>(&Kf[cbase + lr][kc + koff]);
      const half8 b1 = *reinterpret_cast<const half8*>(&Kf[cbase + 16 + lr][kc + koff]);
      aS[0][0] = MFMA16(a0, b0, aS[0][0]); aS[0][1] = MFMA16(a0, b1, aS[0][1]);
      aS[1][0] = MFMA16(a1, b0, aS[1][0]); aS[1][1] = MFMA16(a1, b1, aS[1][1]);
    }
    const bool kv0 = mask[(size_t)b * Tc + s * SPANc + cbase + lr] != 0;
    const bool kv1 = mask[(size_t)b * Tc + s * SPANc + cbase + 16 + lr] != 0;
#pragma unroll
    for (int mi = 0; mi < 2; ++mi)
#pragma unroll
      for (int ni = 0; ni < 2; ++ni) {
        const int col = cbase + ni * 16 + lr;
        const int row0 = rbase + mi * 16 + (lane >> 4) * 4;
        const bool kv = (ni == 0) ? kv0 : kv1;
#pragma unroll
        for (int j = 0; j < 4; ++j)
          sc[row0 + j][col] = kv ? aS[mi][ni][j] * 0.125f : FINF_MIN;
      }
  }
  __syncthreads();

  // ---- row softmax (64 lanes, staggered), write P fp16 ----
  if (tid < 64) {
    float mx = FINF_MIN;
    for (int mm = 0; mm < 64; ++mm) {
      const int m = (mm + tid) & 63;
      mx = fmaxf(mx, sc[tid][m]);
    }
    float sum = 0.f;
    for (int mm = 0; mm < 64; ++mm) {
      const int m = (mm + tid) & 63;
      const float e = expf(sc[tid][m] - mx);
      sc[tid][m] = e;
      sum += e;
    }
    const float inv = 1.f / sum;
    for (int mm = 0; mm < 64; ++mm) {
      const int m = (mm + tid) & 63;
      Pf[tid][m] = (_Float16)(sc[tid][m] * inv);
    }
  }
  __syncthreads();

  // ---- ctx = P V via MFMA (B = VT rows) + store ----
  {
    f32x4 aC[2][2];
#pragma unroll
    for (int mi = 0; mi < 2; ++mi)
#pragma unroll
      for (int ni = 0; ni < 2; ++ni)
#pragma unroll
        for (int j = 0; j < 4; ++j) aC[mi][ni][j] = 0.f;
#pragma unroll
    for (int kc = 0; kc < 64; kc += 32) {
      const half8 a0 = *reinterpret_cast<const half8*>(&Pf[rbase + lr][kc + koff]);
      const half8 a1 = *reinterpret_cast<const half8*>(&Pf[rbase + 16 + lr][kc + koff]);
      const half8 b0 = *reinterpret_cast<const half8*>(&VT[cbase + lr][kc + koff]);
      const half8 b1 = *reinterpret_cast<const half8*>(&VT[cbase + 16 + lr][kc + koff]);
      aC[0][0] = MFMA16(a0, b0, aC[0][0]); aC[0][1] = MFMA16(a0, b1, aC[0][1]);
      aC[1][0] = MFMA16(a1, b0, aC[1][0]); aC[1][1] = MFMA16(a1, b1, aC[1][1]);
    }
    float* ob = out + ((size_t)b * Tc + s * SPANc) * Dc + h * HDc;
#pragma unroll
    for (int mi = 0; mi < 2; ++mi)
#pragma unroll
      for (int ni = 0; ni < 2; ++ni) {
        const int col = cbase + ni * 16 + lr;
        const int row0 = rbase + mi * 16 + (lane >> 4) * 4;
#pragma unroll
        for (int j = 0; j < 4; ++j)
          ob[(size_t)(row0 + j) * Dc + col] = aC[mi][ni][j];
      }
  }
}

// ---------------------------------------------------------------------------
// Fallback (R4 path) if ws is too small for the grouped paths.
// ---------------------------------------------------------------------------
__global__ __launch_bounds__(256, 3) void moe_attn_fb(
    const float* __restrict__ x, const int* __restrict__ mask,
    const float* __restrict__ Wq, const float* __restrict__ Wk,
    const float* __restrict__ Wv,
    const int* __restrict__ eidx, const float* __restrict__ egw,
    float* __restrict__ out)
{
  const int h = blockIdx.x;
  const int s = blockIdx.y;
  const int b = blockIdx.z;
  const int span = b * NSc + s;
  const int tid = threadIdx.x;

  __shared__ __align__(16) char smem[52224];
  _Float16* XF  = (_Float16*)(smem);
  _Float16* WHs = (_Float16*)(smem + 5120);
  _Float16* WLs = (_Float16*)(smem + 10240);
  float* qs = (float*)(smem);
  float* ks = (float*)(smem + 17408);
  float* vs = (float*)(smem + 34816);

  const int e0 = eidx[span * 2 + 0];
  const int e1 = eidx[span * 2 + 1];
  const float g0s = egw[span * 2 + 0] * 64.f;
  const float g1s = egw[span * 2 + 1] * 64.f;

  const int lrow = tid >> 2;
  const int kq = (tid & 3) * 8;
  const int stg_off = lrow * 40 + kq;

  const int w = tid >> 6;
  const int lane = tid & 63;
  const int lr = lane & 15;
  const int koff = (lane >> 4) * 8;
  const int rbase = (w >> 1) * 32;
  const int cbase = (w & 1) * 32;

  const float* xb = x + ((size_t)b * Tc + s * SPANc) * Dc;
  const size_t woff0 = ((size_t)e0 * Dc + h * HDc + lrow) * Dc + kq;
  const size_t woff1 = ((size_t)e1 * Dc + h * HDc + lrow) * Dc + kq;

  const float* xcur  = xb + (size_t)lrow * Dc + kq;
  const float* w0cur = Wv + woff0;
  const float* w1cur = Wv + woff1;
  float4 rx0, rx1, ra0, ra1, rb0, rb1;
  rx0 = LD4(xcur); rx1 = LD4(xcur + 4);
  ra0 = LD4(w0cur); ra1 = LD4(w0cur + 4);
  rb0 = LD4(w1cur); rb1 = LD4(w1cur + 4);

  for (int p = 0; p < 3; ++p) {
    f32x4 acc[2][2];
#pragma unroll
    for (int mi = 0; mi < 2; ++mi)
#pragma unroll
      for (int ni = 0; ni < 2; ++ni)
#pragma unroll
        for (int j = 0; j < 4; ++j) acc[mi][ni][j] = 0.f;

    for (int t = 0; t < 32; ++t) {
      __syncthreads();
      {
        half8 hx;
        hx[0] = (_Float16)rx0.x; hx[1] = (_Float16)rx0.y;
        hx[2] = (_Float16)rx0.z; hx[3] = (_Float16)rx0.w;
        hx[4] = (_Float16)rx1.x; hx[5] = (_Float16)rx1.y;
        hx[6] = (_Float16)rx1.z; hx[7] = (_Float16)rx1.w;
        *reinterpret_cast<half8*>(XF + stg_off) = hx;
      }
      {
        float wv[8];
        wv[0] = g0s * ra0.x + g1s * rb0.x; wv[1] = g0s * ra0.y + g1s * rb0.y;
        wv[2] = g0s * ra0.z + g1s * rb0.z; wv[3] = g0s * ra0.w + g1s * rb0.w;
        wv[4] = g0s * ra1.x + g1s * rb1.x; wv[5] = g0s * ra1.y + g1s * rb1.y;
        wv[6] = g0s * ra1.z + g1s * rb1.z; wv[7] = g0s * ra1.w + g1s * rb1.w;
        half8 hw, lw;
#pragma unroll
        for (int i = 0; i < 8; ++i) {
          const _Float16 wh = (_Float16)wv[i];
          hw[i] = wh;
          lw[i] = (_Float16)(wv[i] - (float)wh);
        }
        *reinterpret_cast<half8*>(WHs + stg_off) = hw;
        *reinterpret_cast<half8*>(WLs + stg_off) = lw;
      }
      if (!(p == 2 && t == 31)) {
        if (t < 31) {
          xcur += 32; w0cur += 32; w1cur += 32;
        } else {
          const float* Wn = (p == 0) ? Wk : Wq;
          xcur = xb + (size_t)lrow * Dc + kq;
          w0cur = Wn + woff0;
          w1cur = Wn + woff1;
        }
        rx0 = LD4(xcur); rx1 = LD4(xcur + 4);
        ra0 = LD4(w0cur); ra1 = LD4(w0cur + 4);
        rb0 = LD4(w1cur); rb1 = LD4(w1cur + 4);
      }
      __syncthreads();

      const half8 a0  = *reinterpret_cast<const half8*>(XF  + (rbase + lr) * 40 + koff);
      const half8 a1  = *reinterpret_cast<const half8*>(XF  + (rbase + 16 + lr) * 40 + koff);
      const half8 bh0 = *reinterpret_cast<const half8*>(WHs + (cbase + lr) * 40 + koff);
      const half8 bh1 = *reinterpret_cast<const half8*>(WHs + (cbase + 16 + lr) * 40 + koff);
      const half8 bl0 = *reinterpret_cast<const half8*>(WLs + (cbase + lr) * 40 + koff);
      const half8 bl1 = *reinterpret_cast<const half8*>(WLs + (cbase + 16 + lr) * 40 + koff);

      acc[0][0] = MFMA16(a0, bh0, acc[0][0]);
      acc[0][1] = MFMA16(a0, bh1, acc[0][1]);
      acc[1][0] = MFMA16(a1, bh0, acc[1][0]);
      acc[1][1] = MFMA16(a1, bh1, acc[1][1]);
      acc[0][0] = MFMA16(a0, bl0, acc[0][0]);
      acc[0][1] = MFMA16(a0, bl1, acc[0][1]);
      acc[1][0] = MFMA16(a1, bl0, acc[1][0]);
      acc[1][1] = MFMA16(a1, bl1, acc[1][1]);
    }

    float* dst = (p == 0) ? vs : (p == 1) ? ks : qs;
    if (p == 2) __syncthreads();
#pragma unroll
    for (int mi = 0; mi < 2; ++mi)
#pragma unroll
      for (int ni = 0; ni < 2; ++ni) {
        const int col = cbase + ni * 16 + lr;
        const int row0 = rbase + mi * 16 + (lane >> 4) * 4;
#pragma unroll
        for (int j = 0; j < 4; ++j)
          dst[(row0 + j) * 68 + col] = acc[mi][ni][j] * 0.015625f;
      }
  }
  __syncthreads();

  const int tx = tid & 15;
  const int ty = tid >> 4;
  bool kvalid[4];
#pragma unroll
  for (int j = 0; j < 4; ++j)
    kvalid[j] = mask[(size_t)b * Tc + s * SPANc + tx * 4 + j] != 0;

  float sacc[4][4] = {{0.f, 0.f, 0.f, 0.f}, {0.f, 0.f, 0.f, 0.f},
                      {0.f, 0.f, 0.f, 0.f}, {0.f, 0.f, 0.f, 0.f}};
  for (int dd = 0; dd < 64; ++dd) {
    const int d = (dd + tid) & 63;
    const float a0 = qs[(ty * 4 + 0) * 68 + d], a1 = qs[(ty * 4 + 1) * 68 + d];
    const float a2 = qs[(ty * 4 + 2) * 68 + d], a3 = qs[(ty * 4 + 3) * 68 + d];
    const float b0 = ks[(tx * 4 + 0) * 68 + d], b1v = ks[(tx * 4 + 1) * 68 + d];
    const float b2v = ks[(tx * 4 + 2) * 68 + d], b3 = ks[(tx * 4 + 3) * 68 + d];
    sacc[0][0] += a0 * b0; sacc[0][1] += a0 * b1v; sacc[0][2] += a0 * b2v; sacc[0][3] += a0 * b3;
    sacc[1][0] += a1 * b0; sacc[1][1] += a1 * b1v; sacc[1][2] += a1 * b2v; sacc[1][3] += a1 * b3;
    sacc[2][0] += a2 * b0; sacc[2][1] += a2 * b1v; sacc[2][2] += a2 * b2v; sacc[2][3] += a2 * b3;
    sacc[3][0] += a3 * b0; sacc[3][1] += a3 * b1v; sacc[3][2] += a3 * b2v; sacc[3][3] += a3 * b3;
  }
  __syncthreads();
#pragma unroll
  for (int i = 0; i < 4; ++i)
#pragma unroll
    for (int j = 0; j < 4; ++j)
      qs[(ty * 4 + i) * 68 + tx * 4 + j] = kvalid[j] ? sacc[i][j] * 0.125f : FINF_MIN;
  __syncthreads();

  if (tid < 64) {
    float mx = FINF_MIN;
    for (int mm = 0; mm < 64; ++mm) {
      const int m = (mm + tid) & 63;
      mx = fmaxf(mx, qs[tid * 68 + m]);
    }
    float sum = 0.f;
    for (int mm = 0; mm < 64; ++mm) {
      const int m = (mm + tid) & 63;
      const float e = expf(qs[tid * 68 + m] - mx);
      qs[tid * 68 + m] = e;
      sum += e;
    }
    const float inv = 1.f / sum;
    for (int mm = 0; mm < 64; ++mm) {
      const int m = (mm + tid) & 63;
      qs[tid * 68 + m] *= inv;
    }
  }
  __syncthreads();

  float cacc[4][4] = {{0.f, 0.f, 0.f, 0.f}, {0.f, 0.f, 0.f, 0.f},
                      {0.f, 0.f, 0.f, 0.f}, {0.f, 0.f, 0.f, 0.f}};
  for (int m = 0; m < 64; ++m) {
    const float p0 = qs[(ty * 4 + 0) * 68 + m], p1 = qs[(ty * 4 + 1) * 68 + m];
    const float p2 = qs[(ty * 4 + 2) * 68 + m], p3 = qs[(ty * 4 + 3) * 68 + m];
    const float4 vv = *reinterpret_cast<const float4*>(&vs[m * 68 + tx * 4]);
    cacc[0][0] += p0 * vv.x; cacc[0][1] += p0 * vv.y; cacc[0][2] += p0 * vv.z; cacc[0][3] += p0 * vv.w;
    cacc[1][0] += p1 * vv.x; cacc[1][1] += p1 * vv.y; cacc[1][2] += p1 * vv.z; cacc[1][3] += p1 * vv.w;
    cacc[2][0] += p2 * vv.x; cacc[2][1] += p2 * vv.y; cacc[2][2] += p2 * vv.z; cacc[2][3] += p2 * vv.w;
    cacc[3][0] += p3 * vv.x; cacc[3][1] += p3 * vv.y; cacc[3][2] += p3 * vv.z; cacc[3][3] += p3 * vv.w;
  }

  float* ob = out + ((size_t)b * Tc + s * SPANc) * Dc + h * HDc;
#pragma unroll
  for (int i = 0; i < 4; ++i) {
    *reinterpret_cast<float4*>(ob + (size_t)(ty * 4 + i) * Dc + tx * 4) =
        make_float4(cacc[i][0], cacc[i][1], cacc[i][2], cacc[i][3]);
  }
}

// ---------------------------------------------------------------------------
extern "C" void kernel_launch(void* const* d_in, const int* in_sizes, int n_in,
                              void* d_out, int out_size, void* d_ws, size_t ws_size,
                              hipStream_t stream) {
  const float* x   = (const float*)d_in[0];
  const int*   msk = (const int*)d_in[1];
  const float* Wq  = (const float*)d_in[2];
  const float* Wk  = (const float*)d_in[3];
  const float* Wv  = (const float*)d_in[4];
  const float* w1  = (const float*)d_in[5];
  const float* b1  = (const float*)d_in[6];
  const float* w2  = (const float*)d_in[7];
  const float* b2  = (const float*)d_in[8];
  float* out = (float*)d_out;

  char* ws = (char*)d_ws;
  int*      eidx   = (int*)(ws + OFF_EIDX);
  float*    egw    = (float*)(ws + OFF_EGW);
  int*      nmt    = (int*)(ws + OFF_NMT);
  int*      mtiles = (int*)(ws + OFF_MT);
  _Float16* Ut     = (_Float16*)(ws + OFF_UT);
  _Float16* W16    = (_Float16*)(ws + OFF_W16);

  if (ws_size >= WS_W16) {
    gate_cvt_kernel<<<NSPAN + CVT_BLOCKS, 256, 0, stream>>>(
        x, msk, w1, b1, w2, b2, Wq, Wk, Wv, eidx, egw, W16);
    bookkeep_kernel<<<1, 64, 0, stream>>>(eidx, nmt, mtiles);
    moe_gemm_w16<<<GRID_W16, 512, 0, stream>>>(x, W16, nmt, mtiles, Ut);
    attn_kernel<<<dim3(Hc, NSc, Bc), 256, 0, stream>>>(msk, egw, Ut, out);
  } else if (ws_size >= WS_MID) {
    gate_cvt_kernel<<<NSPAN, 256, 0, stream>>>(
        x, msk, w1, b1, w2, b2, Wq, Wk, Wv, eidx, egw, nullptr);
    bookkeep_kernel<<<1, 64, 0, stream>>>(eidx, nmt, mtiles);
    moe_gemm_f32<<<dim3(MAXMT, NTILES), 512, 0, stream>>>(
        x, Wq, Wk, Wv, nmt, mtiles, Ut);
    attn_kernel<<<dim3(Hc, NSc, Bc), 256, 0, stream>>>(msk, egw, Ut, out);
  } else {
    gate_cvt_kernel<<<NSPAN, 256, 0, stream>>>(
        x, msk, w1, b1, w2, b2, Wq, Wk, Wv, eidx, egw, nullptr);
    moe_attn_fb<<<dim3(Hc, NSc, Bc), 256, 0, stream>>>(
        x, msk, Wq, Wk, Wv, eidx, egw, out);
  }
}